// Round 9
// baseline (136.439 us; speedup 1.0000x reference)
//
#include <hip/hip_runtime.h>
#include <cstdint>
#include <cmath>

#define B_    8
#define SMAX  4096
#define E_    4096
#define H_    32
#define D_    128
#define TOPK  8
#define NPAIR (B_*TOPK)
#define CHUNK 128
#define NCHUNK (SMAX/CHUNK)   // 32

// workspace layout (in floats)
#define WS_QKV  0                              // NPAIR*384 : per pair {q[128], k_new[128], v_new[128]}
#define WS_M    (WS_QKV + NPAIR*384)           // NPAIR*NCHUNK
#define WS_L    (WS_M + NPAIR*NCHUNK)          // NPAIR*NCHUNK
#define WS_PCTX (WS_L + NPAIR*NCHUNK)          // NPAIR*NCHUNK*D_
#define WS_CTX  (WS_PCTX + (size_t)NPAIR*NCHUNK*D_)    // NPAIR*D_

// ---------------- kernel 1: qkv rows; 1 row per block, quarter-row per wave ----------
// Low VGPR (<=64 via launch_bounds) -> 32 waves/CU for max outstanding HBM loads.
__global__ __launch_bounds__(256, 8) void k_qkv(const float* __restrict__ x,
    const float* __restrict__ w_qkv, const float* __restrict__ b_qkv,
    const int* __restrict__ bhi, float* __restrict__ ws)
{
    int gid = blockIdx.x;         // 0..12287
    int h = gid / 384;            // head
    int r = gid % 384;            // row 0..383 (0=q 1=k 2=v blocks of 128)

    __shared__ int hs_s[B_*TOPK];
    __shared__ int nsel_s;
    __shared__ int sel_s[B_];     // packed (b<<8)|slot
    __shared__ float part[4][B_];
    if (threadIdx.x < B_*TOPK) hs_s[threadIdx.x] = bhi[threadIdx.x];
    if (threadIdx.x == 0) nsel_s = 0;
    __syncthreads();
    if (threadIdx.x < B_) {
        int b = threadIdx.x;
        for (int j = 0; j < TOPK; ++j) {
            if (hs_s[b*TOPK + j] == h) {
                int idx = atomicAdd(&nsel_s, 1);
                sel_s[idx] = (b << 8) | j;
                break;
            }
        }
    }
    __syncthreads();
    int nsel = nsel_s;
    if (nsel == 0) return;

    int wid = threadIdx.x >> 6, lane = threadIdx.x & 63;
    int mat = r >> 7, rr = r & 127;
    int wrow = mat*E_ + h*D_ + rr;

    // quarter row in registers: 4 float4 per lane (16 VGPR)
    const float4* wp = (const float4*)(w_qkv + (size_t)wrow * E_) + wid*256;
    float4 wf[4];
    #pragma unroll
    for (int i = 0; i < 4; ++i) wf[i] = wp[i*64 + lane];

    for (int is = 0; is < nsel; ++is) {
        int b = sel_s[is] >> 8;
        const float4* xp = (const float4*)(x + (size_t)b * E_) + wid*256;
        float4 a = make_float4(0.f, 0.f, 0.f, 0.f);
        #pragma unroll
        for (int i = 0; i < 4; ++i) {
            float4 xv = xp[i*64 + lane];
            a.x += wf[i].x*xv.x; a.y += wf[i].y*xv.y;
            a.z += wf[i].z*xv.z; a.w += wf[i].w*xv.w;
        }
        float acc = (a.x + a.y) + (a.z + a.w);
        for (int o = 32; o > 0; o >>= 1) acc += __shfl_down(acc, o);
        if (lane == 0) part[wid][is] = acc;
    }
    __syncthreads();
    if (threadIdx.x < (unsigned)nsel) {
        int is = threadIdx.x;
        int b = sel_s[is] >> 8, slot = sel_s[is] & 255;
        int pair = b*TOPK + slot;
        float v = part[0][is] + part[1][is] + part[2][is] + part[3][is];
        ws[WS_QKV + pair*384 + r] = v + b_qkv[wrow];
    }
}

// ---------------- kernel 2: partial flash attention per (pair, chunk) ----------------
__global__ __launch_bounds__(256) void k_attn(const float* __restrict__ kv,
    const int* __restrict__ bhi, const int* __restrict__ seqoff,
    float* __restrict__ ws)
{
    int pair = blockIdx.x >> 5, chunk = blockIdx.x & (NCHUNK - 1);
    int b = pair >> 3, slot = pair & 7;
    int h = bhi[b*TOPK + slot];
    for (int j = 0; j < slot; ++j) if (bhi[b*TOPK + j] == h) return;  // dup: block exits
    int S = seqoff[0] + 1;

    __shared__ __align__(16) float4 q4_s[32];
    __shared__ float wts[CHUNK];
    __shared__ float red[8];
    __shared__ __align__(16) float4 vred[8][32];

    int tid = threadIdx.x;
    if (tid < 32) q4_s[tid] = ((const float4*)(ws + WS_QKV + pair*384))[tid];
    __syncthreads();

    // ---- K-pass: pos = tid>>1 in 0..127, dh = tid&1 covers half the dot each ----
    int pos = tid >> 1, dh = tid & 1;
    int s = chunk*CHUNK + pos;
    bool valid = s < S;
    float sc = 0.f;
    if (valid) {
        const float4* kp = (s == S - 1)
            ? (const float4*)(ws + WS_QKV + pair*384 + 128)
            : (const float4*)(kv + ((((size_t)b*SMAX + s)*2 + 0)*H_ + h) * (size_t)D_);
        kp += dh*16;
        #pragma unroll
        for (int i = 0; i < 16; ++i) {
            float4 kvv = kp[i]; float4 qv = q4_s[dh*16 + i];
            sc += kvv.x*qv.x + kvv.y*qv.y + kvv.z*qv.z + kvv.w*qv.w;
        }
    }
    sc += __shfl_xor(sc, 1);                       // both lanes now hold full dot
    float score = valid ? sc * 0.08838834764831845f : -1e30f;

    // block max (duplicates don't affect max)
    float m = score;
    for (int o = 32; o > 0; o >>= 1) m = fmaxf(m, __shfl_down(m, o));
    int wid = tid >> 6, lane = tid & 63;
    if (lane == 0) red[wid] = m;
    __syncthreads();
    if (tid == 0) red[4] = fmaxf(fmaxf(red[0], red[1]), fmaxf(red[2], red[3]));
    __syncthreads();
    m = red[4];
    float w = (valid && dh == 0) ? expf(score - m) : 0.f;
    if (dh == 0) wts[pos] = w;
    // block sum (only dh==0 contributes)
    float l = w;
    for (int o = 32; o > 0; o >>= 1) l += __shfl_down(l, o);
    if (lane == 0) red[wid] = l;
    __syncthreads();
    if (tid == 0) red[5] = red[0] + red[1] + red[2] + red[3];
    __syncthreads();

    // ---- V-pass: d4 = tid&31 (float4 column), grp = tid>>5 (8 groups x 16 positions) ----
    int d4 = tid & 31, grp = tid >> 5;
    float4 acc = make_float4(0.f, 0.f, 0.f, 0.f);
    #pragma unroll 4
    for (int i = 0; i < 16; ++i) {
        int t = grp*16 + i;
        int s2 = chunk*CHUNK + t;
        if (s2 < S) {
            const float4* vp = (s2 == S - 1)
                ? (const float4*)(ws + WS_QKV + pair*384 + 256)
                : (const float4*)(kv + ((((size_t)b*SMAX + s2)*2 + 1)*H_ + h) * (size_t)D_);
            float4 vv = vp[d4];
            float wt = wts[t];
            acc.x += wt*vv.x; acc.y += wt*vv.y; acc.z += wt*vv.z; acc.w += wt*vv.w;
        }
    }
    vred[grp][d4] = acc;
    __syncthreads();

    int pc = pair*NCHUNK + chunk;
    if (tid < 32) {
        float4 r = vred[0][tid];
        #pragma unroll
        for (int g = 1; g < 8; ++g) {
            float4 o = vred[g][tid];
            r.x += o.x; r.y += o.y; r.z += o.z; r.w += o.w;
        }
        ((float4*)(ws + WS_PCTX + (size_t)pc*D_))[tid] = r;
    }
    if (tid == 0) { ws[WS_M + pc] = red[4]; ws[WS_L + pc] = red[5]; }
}

// ---------------- kernel 3: combine partials (online softmax merge) ----------------
__global__ __launch_bounds__(128) void k_comb(const int* __restrict__ bhi,
    float* __restrict__ ws)
{
    int pair = blockIdx.x;
    int b = pair >> 3, slot = pair & 7;
    int tid = threadIdx.x;
    int h = bhi[b*TOPK + slot];
    bool dup = false;
    for (int j = 0; j < slot; ++j) if (bhi[b*TOPK + j] == h) dup = true;
    if (dup) { ws[WS_CTX + pair*D_ + tid] = 0.f; return; }

    __shared__ float m_s[NCHUNK], l_s[NCHUNK];
    if (tid < NCHUNK) {
        m_s[tid] = ws[WS_M + pair*NCHUNK + tid];
        l_s[tid] = ws[WS_L + pair*NCHUNK + tid];
    }
    __syncthreads();
    float M = -1e30f;
    for (int i = 0; i < NCHUNK; ++i) M = fmaxf(M, m_s[i]);
    float L = 0.f;
    for (int i = 0; i < NCHUNK; ++i) L += l_s[i] * expf(m_s[i] - M);
    float acc = 0.f;
    for (int i = 0; i < NCHUNK; ++i)
        acc += ws[WS_PCTX + (size_t)(pair*NCHUNK + i)*D_ + tid] * expf(m_s[i] - M);
    ws[WS_CTX + pair*D_ + tid] = acc / L;
}

// ---------------- kernel 4: output projection, thread = (f, slot), 16 waves/CU ----------
__global__ __launch_bounds__(256) void k_out(const float* __restrict__ w_out,
    const float* __restrict__ b_out, const int* __restrict__ bhi,
    const float* __restrict__ ws, float* __restrict__ out)
{
    int b = blockIdx.x >> 7, fblk = blockIdx.x & 127;
    int tid = threadIdx.x;
    int f_local = tid >> 3, slot = tid & 7;
    int f = fblk*32 + f_local;

    __shared__ __align__(16) float ctx_s[TOPK*D_];
    __shared__ int h_s[TOPK];
    __shared__ int dup_s[TOPK];
    ((float4*)ctx_s)[tid] = ((const float4*)(ws + WS_CTX + (size_t)b*TOPK*D_))[tid];
    if (tid < TOPK) {
        int h = bhi[b*TOPK + tid]; h_s[tid] = h;
        int dup = 0;
        for (int j = 0; j < tid; ++j) if (bhi[b*TOPK + j] == h) dup = 1;
        dup_s[tid] = dup;
    }
    __syncthreads();

    float acc = 0.f;
    if (!dup_s[slot]) {
        const float4* wp = (const float4*)(w_out + (size_t)f*E_ + h_s[slot]*D_);
        const float4* cp = (const float4*)(ctx_s + slot*D_);
        #pragma unroll
        for (int i = 0; i < 32; ++i) {
            float4 wv = wp[i]; float4 cv = cp[i];
            acc += wv.x*cv.x + wv.y*cv.y + wv.z*cv.z + wv.w*cv.w;
        }
    }
    acc += __shfl_down(acc, 4, 8);
    acc += __shfl_down(acc, 2, 8);
    acc += __shfl_down(acc, 1, 8);
    if (slot == 0) out[(size_t)b*E_ + f] = acc + b_out[f];
}

extern "C" void kernel_launch(void* const* d_in, const int* in_sizes, int n_in,
                              void* d_out, int out_size, void* d_ws, size_t ws_size,
                              hipStream_t stream) {
    const float* x      = (const float*)d_in[0];
    const float* kv     = (const float*)d_in[1];
    const float* w_qkv  = (const float*)d_in[2];
    const float* b_qkv  = (const float*)d_in[3];
    const float* w_out  = (const float*)d_in[4];
    const float* b_out  = (const float*)d_in[5];
    const int*   bhi    = (const int*)d_in[6];
    const int*   seqoff = (const int*)d_in[7];
    float* ws  = (float*)d_ws;
    float* out = (float*)d_out;

    hipLaunchKernelGGL(k_qkv,  dim3(32*384),       dim3(256), 0, stream, x, w_qkv, b_qkv, bhi, ws);
    hipLaunchKernelGGL(k_attn, dim3(NPAIR*NCHUNK), dim3(256), 0, stream, kv, bhi, seqoff, ws);
    hipLaunchKernelGGL(k_comb, dim3(NPAIR),        dim3(128), 0, stream, bhi, ws);
    hipLaunchKernelGGL(k_out,  dim3(B_*128),       dim3(256), 0, stream, w_out, b_out, bhi, ws, out);
}

// Round 10
// 127.034 us; speedup vs baseline: 1.0740x; 1.0740x over previous
//
#include <hip/hip_runtime.h>
#include <cstdint>
#include <cmath>

#define B_    8
#define SMAX  4096
#define E_    4096
#define H_    32
#define D_    128
#define TOPK  8
#define NPAIR (B_*TOPK)
#define CHUNK 64
#define NCHUNK (SMAX/CHUNK)   // 64

// workspace layout (in floats)
#define WS_QKV  0                              // NPAIR*384 : per pair {q[128], k_new[128], v_new[128]}
#define WS_M    (WS_QKV + NPAIR*384)           // NPAIR*NCHUNK
#define WS_L    (WS_M + NPAIR*NCHUNK)          // NPAIR*NCHUNK
#define WS_PCTX (WS_L + NPAIR*NCHUNK)          // NPAIR*NCHUNK*D_
#define WS_CTX  (WS_PCTX + (size_t)NPAIR*NCHUNK*D_)    // NPAIR*D_

// ---------------- kernel 1: qkv rows; 1 row per block, quarter-row per wave ----------
__global__ __launch_bounds__(256, 8) void k_qkv(const float* __restrict__ x,
    const float* __restrict__ w_qkv, const float* __restrict__ b_qkv,
    const int* __restrict__ bhi, float* __restrict__ ws)
{
    int gid = blockIdx.x;         // 0..12287
    int h = gid / 384;            // head
    int r = gid % 384;            // row 0..383 (0=q 1=k 2=v blocks of 128)

    __shared__ int hs_s[B_*TOPK];
    __shared__ int nsel_s;
    __shared__ int sel_s[B_];     // packed (b<<8)|slot
    __shared__ float part[4][B_];
    if (threadIdx.x < B_*TOPK) hs_s[threadIdx.x] = bhi[threadIdx.x];
    if (threadIdx.x == 0) nsel_s = 0;
    __syncthreads();
    if (threadIdx.x < B_) {
        int b = threadIdx.x;
        for (int j = 0; j < TOPK; ++j) {
            if (hs_s[b*TOPK + j] == h) {
                int idx = atomicAdd(&nsel_s, 1);
                sel_s[idx] = (b << 8) | j;
                break;
            }
        }
    }
    __syncthreads();
    int nsel = nsel_s;
    if (nsel == 0) return;

    int wid = threadIdx.x >> 6, lane = threadIdx.x & 63;
    int mat = r >> 7, rr = r & 127;
    int wrow = mat*E_ + h*D_ + rr;

    // quarter row in registers: 4 float4 per lane (16 VGPR)
    const float4* wp = (const float4*)(w_qkv + (size_t)wrow * E_) + wid*256;
    float4 wf[4];
    #pragma unroll
    for (int i = 0; i < 4; ++i) wf[i] = wp[i*64 + lane];

    for (int is = 0; is < nsel; ++is) {
        int b = sel_s[is] >> 8;
        const float4* xp = (const float4*)(x + (size_t)b * E_) + wid*256;
        float4 a = make_float4(0.f, 0.f, 0.f, 0.f);
        #pragma unroll
        for (int i = 0; i < 4; ++i) {
            float4 xv = xp[i*64 + lane];
            a.x += wf[i].x*xv.x; a.y += wf[i].y*xv.y;
            a.z += wf[i].z*xv.z; a.w += wf[i].w*xv.w;
        }
        float acc = (a.x + a.y) + (a.z + a.w);
        for (int o = 32; o > 0; o >>= 1) acc += __shfl_down(acc, o);
        if (lane == 0) part[wid][is] = acc;
    }
    __syncthreads();
    if (threadIdx.x < (unsigned)nsel) {
        int is = threadIdx.x;
        int b = sel_s[is] >> 8, slot = sel_s[is] & 255;
        int pair = b*TOPK + slot;
        float v = part[0][is] + part[1][is] + part[2][is] + part[3][is];
        ws[WS_QKV + pair*384 + r] = v + b_qkv[wrow];
    }
}

// ---------------- kernel 2: partial flash attention per (pair, chunk) ----------------
// CHUNK=64, grid = NPAIR*64 = 4096 blocks. K-pass: 4 threads/position x 8 float4.
// V-pass: 8 groups x 8 positions, float4 columns.
__global__ __launch_bounds__(256) void k_attn(const float* __restrict__ kv,
    const int* __restrict__ bhi, const int* __restrict__ seqoff,
    float* __restrict__ ws)
{
    int pair = blockIdx.x >> 6, chunk = blockIdx.x & (NCHUNK - 1);
    int b = pair >> 3, slot = pair & 7;
    int h = bhi[b*TOPK + slot];
    for (int j = 0; j < slot; ++j) if (bhi[b*TOPK + j] == h) return;  // dup: block exits
    int S = seqoff[0] + 1;

    __shared__ __align__(16) float4 q4_s[32];
    __shared__ float wts[CHUNK];
    __shared__ float red[8];
    __shared__ __align__(16) float4 vred[8][32];

    int tid = threadIdx.x;
    if (tid < 32) q4_s[tid] = ((const float4*)(ws + WS_QKV + pair*384))[tid];
    __syncthreads();

    // ---- K-pass: pos = tid>>2 in 0..63, dq = tid&3 covers a quarter of the dot ----
    int pos = tid >> 2, dq = tid & 3;
    int s = chunk*CHUNK + pos;
    bool valid = s < S;
    float sc = 0.f;
    if (valid) {
        const float4* kp = (s == S - 1)
            ? (const float4*)(ws + WS_QKV + pair*384 + 128)
            : (const float4*)(kv + ((((size_t)b*SMAX + s)*2 + 0)*H_ + h) * (size_t)D_);
        kp += dq*8;
        #pragma unroll
        for (int i = 0; i < 8; ++i) {
            float4 kvv = kp[i]; float4 qv = q4_s[dq*8 + i];
            sc += kvv.x*qv.x + kvv.y*qv.y + kvv.z*qv.z + kvv.w*qv.w;
        }
    }
    sc += __shfl_xor(sc, 1);
    sc += __shfl_xor(sc, 2);                       // all 4 lanes hold full dot
    float score = valid ? sc * 0.08838834764831845f : -1e30f;

    // block max
    float m = score;
    for (int o = 32; o > 0; o >>= 1) m = fmaxf(m, __shfl_down(m, o));
    int wid = tid >> 6, lane = tid & 63;
    if (lane == 0) red[wid] = m;
    __syncthreads();
    if (tid == 0) red[4] = fmaxf(fmaxf(red[0], red[1]), fmaxf(red[2], red[3]));
    __syncthreads();
    m = red[4];
    float w = (valid && dq == 0) ? expf(score - m) : 0.f;
    if (dq == 0) wts[pos] = w;
    // block sum (only dq==0 contributes)
    float l = w;
    for (int o = 32; o > 0; o >>= 1) l += __shfl_down(l, o);
    if (lane == 0) red[wid] = l;
    __syncthreads();
    if (tid == 0) red[5] = red[0] + red[1] + red[2] + red[3];
    __syncthreads();

    // ---- V-pass: d4 = tid&31 (float4 column), grp = tid>>5 (8 groups x 8 positions) ----
    int d4 = tid & 31, grp = tid >> 5;
    float4 acc = make_float4(0.f, 0.f, 0.f, 0.f);
    #pragma unroll
    for (int i = 0; i < 8; ++i) {
        int t = grp*8 + i;
        int s2 = chunk*CHUNK + t;
        if (s2 < S) {
            const float4* vp = (s2 == S - 1)
                ? (const float4*)(ws + WS_QKV + pair*384 + 256)
                : (const float4*)(kv + ((((size_t)b*SMAX + s2)*2 + 1)*H_ + h) * (size_t)D_);
            float4 vv = vp[d4];
            float wt = wts[t];
            acc.x += wt*vv.x; acc.y += wt*vv.y; acc.z += wt*vv.z; acc.w += wt*vv.w;
        }
    }
    vred[grp][d4] = acc;
    __syncthreads();

    int pc = pair*NCHUNK + chunk;
    if (tid < 32) {
        float4 r = vred[0][tid];
        #pragma unroll
        for (int g = 1; g < 8; ++g) {
            float4 o = vred[g][tid];
            r.x += o.x; r.y += o.y; r.z += o.z; r.w += o.w;
        }
        ((float4*)(ws + WS_PCTX + (size_t)pc*D_))[tid] = r;
    }
    if (tid == 0) { ws[WS_M + pc] = red[4]; ws[WS_L + pc] = red[5]; }
}

// ---------------- kernel 3: combine partials (online softmax merge) ----------------
__global__ __launch_bounds__(128) void k_comb(const int* __restrict__ bhi,
    float* __restrict__ ws)
{
    int pair = blockIdx.x;
    int b = pair >> 3, slot = pair & 7;
    int tid = threadIdx.x;
    int h = bhi[b*TOPK + slot];
    bool dup = false;
    for (int j = 0; j < slot; ++j) if (bhi[b*TOPK + j] == h) dup = true;
    if (dup) { ws[WS_CTX + pair*D_ + tid] = 0.f; return; }

    __shared__ float m_s[NCHUNK], l_s[NCHUNK];
    if (tid < NCHUNK) {
        m_s[tid] = ws[WS_M + pair*NCHUNK + tid];
        l_s[tid] = ws[WS_L + pair*NCHUNK + tid];
    }
    __syncthreads();
    float M = -1e30f;
    for (int i = 0; i < NCHUNK; ++i) M = fmaxf(M, m_s[i]);
    float L = 0.f;
    for (int i = 0; i < NCHUNK; ++i) L += l_s[i] * expf(m_s[i] - M);
    float acc = 0.f;
    for (int i = 0; i < NCHUNK; ++i)
        acc += ws[WS_PCTX + (size_t)(pair*NCHUNK + i)*D_ + tid] * expf(m_s[i] - M);
    ws[WS_CTX + pair*D_ + tid] = acc / L;
}

// ---------------- kernel 4: output projection, thread = (f, slot), 16 waves/CU ----------
__global__ __launch_bounds__(256) void k_out(const float* __restrict__ w_out,
    const float* __restrict__ b_out, const int* __restrict__ bhi,
    const float* __restrict__ ws, float* __restrict__ out)
{
    int b = blockIdx.x >> 7, fblk = blockIdx.x & 127;
    int tid = threadIdx.x;
    int f_local = tid >> 3, slot = tid & 7;
    int f = fblk*32 + f_local;

    __shared__ __align__(16) float ctx_s[TOPK*D_];
    __shared__ int h_s[TOPK];
    __shared__ int dup_s[TOPK];
    ((float4*)ctx_s)[tid] = ((const float4*)(ws + WS_CTX + (size_t)b*TOPK*D_))[tid];
    if (tid < TOPK) {
        int h = bhi[b*TOPK + tid]; h_s[tid] = h;
        int dup = 0;
        for (int j = 0; j < tid; ++j) if (bhi[b*TOPK + j] == h) dup = 1;
        dup_s[tid] = dup;
    }
    __syncthreads();

    float acc = 0.f;
    if (!dup_s[slot]) {
        const float4* wp = (const float4*)(w_out + (size_t)f*E_ + h_s[slot]*D_);
        const float4* cp = (const float4*)(ctx_s + slot*D_);
        #pragma unroll
        for (int i = 0; i < 32; ++i) {
            float4 wv = wp[i]; float4 cv = cp[i];
            acc += wv.x*cv.x + wv.y*cv.y + wv.z*cv.z + wv.w*cv.w;
        }
    }
    acc += __shfl_down(acc, 4, 8);
    acc += __shfl_down(acc, 2, 8);
    acc += __shfl_down(acc, 1, 8);
    if (slot == 0) out[(size_t)b*E_ + f] = acc + b_out[f];
}

extern "C" void kernel_launch(void* const* d_in, const int* in_sizes, int n_in,
                              void* d_out, int out_size, void* d_ws, size_t ws_size,
                              hipStream_t stream) {
    const float* x      = (const float*)d_in[0];
    const float* kv     = (const float*)d_in[1];
    const float* w_qkv  = (const float*)d_in[2];
    const float* b_qkv  = (const float*)d_in[3];
    const float* w_out  = (const float*)d_in[4];
    const float* b_out  = (const float*)d_in[5];
    const int*   bhi    = (const int*)d_in[6];
    const int*   seqoff = (const int*)d_in[7];
    float* ws  = (float*)d_ws;
    float* out = (float*)d_out;

    hipLaunchKernelGGL(k_qkv,  dim3(32*384),       dim3(256), 0, stream, x, w_qkv, b_qkv, bhi, ws);
    hipLaunchKernelGGL(k_attn, dim3(NPAIR*NCHUNK), dim3(256), 0, stream, kv, bhi, seqoff, ws);
    hipLaunchKernelGGL(k_comb, dim3(NPAIR),        dim3(128), 0, stream, bhi, ws);
    hipLaunchKernelGGL(k_out,  dim3(B_*128),       dim3(256), 0, stream, w_out, b_out, bhi, ws, out);
}

// Round 11
// 116.682 us; speedup vs baseline: 1.1693x; 1.0887x over previous
//
#include <hip/hip_runtime.h>
#include <cstdint>
#include <cmath>

#define B_    8
#define SMAX  4096
#define E_    4096
#define H_    32
#define D_    128
#define TOPK  8
#define NPAIR (B_*TOPK)
#define CHUNK 64
#define NCHUNK (SMAX/CHUNK)   // 64

// workspace layout (in floats)
#define WS_QKV  0                              // NPAIR*384 : per pair {q[128], k_new[128], v_new[128]}
#define WS_M    (WS_QKV + NPAIR*384)           // NPAIR*NCHUNK
#define WS_L    (WS_M + NPAIR*NCHUNK)          // NPAIR*NCHUNK
#define WS_PCTX (WS_L + NPAIR*NCHUNK)          // NPAIR*NCHUNK*D_
#define WS_CTX  (WS_PCTX + (size_t)NPAIR*NCHUNK*D_)    // NPAIR*D_

// ---------------- kernel 1: qkv rows; 1 row per block, quarter-row per wave ----------
__global__ __launch_bounds__(256, 8) void k_qkv(const float* __restrict__ x,
    const float* __restrict__ w_qkv, const float* __restrict__ b_qkv,
    const int* __restrict__ bhi, float* __restrict__ ws)
{
    int gid = blockIdx.x;         // 0..12287
    int h = gid / 384;            // head
    int r = gid % 384;            // row 0..383 (0=q 1=k 2=v blocks of 128)

    __shared__ int hs_s[B_*TOPK];
    __shared__ int nsel_s;
    __shared__ int sel_s[B_];     // packed (b<<8)|slot
    __shared__ float part[4][B_];
    if (threadIdx.x < B_*TOPK) hs_s[threadIdx.x] = bhi[threadIdx.x];
    if (threadIdx.x == 0) nsel_s = 0;
    __syncthreads();
    if (threadIdx.x < B_) {
        int b = threadIdx.x;
        for (int j = 0; j < TOPK; ++j) {
            if (hs_s[b*TOPK + j] == h) {
                int idx = atomicAdd(&nsel_s, 1);
                sel_s[idx] = (b << 8) | j;
                break;
            }
        }
    }
    __syncthreads();
    int nsel = nsel_s;
    if (nsel == 0) return;

    int wid = threadIdx.x >> 6, lane = threadIdx.x & 63;
    int mat = r >> 7, rr = r & 127;
    int wrow = mat*E_ + h*D_ + rr;

    // quarter row in registers: 4 float4 per lane (16 VGPR)
    const float4* wp = (const float4*)(w_qkv + (size_t)wrow * E_) + wid*256;
    float4 wf[4];
    #pragma unroll
    for (int i = 0; i < 4; ++i) wf[i] = wp[i*64 + lane];

    for (int is = 0; is < nsel; ++is) {
        int b = sel_s[is] >> 8;
        const float4* xp = (const float4*)(x + (size_t)b * E_) + wid*256;
        float4 a = make_float4(0.f, 0.f, 0.f, 0.f);
        #pragma unroll
        for (int i = 0; i < 4; ++i) {
            float4 xv = xp[i*64 + lane];
            a.x += wf[i].x*xv.x; a.y += wf[i].y*xv.y;
            a.z += wf[i].z*xv.z; a.w += wf[i].w*xv.w;
        }
        float acc = (a.x + a.y) + (a.z + a.w);
        for (int o = 32; o > 0; o >>= 1) acc += __shfl_down(acc, o);
        if (lane == 0) part[wid][is] = acc;
    }
    __syncthreads();
    if (threadIdx.x < (unsigned)nsel) {
        int is = threadIdx.x;
        int b = sel_s[is] >> 8, slot = sel_s[is] & 255;
        int pair = b*TOPK + slot;
        float v = part[0][is] + part[1][is] + part[2][is] + part[3][is];
        ws[WS_QKV + pair*384 + r] = v + b_qkv[wrow];
    }
}

// ---------------- kernel 2: partial flash attention per (pair, chunk) ----------------
__global__ __launch_bounds__(256) void k_attn(const float* __restrict__ kv,
    const int* __restrict__ bhi, const int* __restrict__ seqoff,
    float* __restrict__ ws)
{
    int pair = blockIdx.x >> 6, chunk = blockIdx.x & (NCHUNK - 1);
    int b = pair >> 3, slot = pair & 7;
    int h = bhi[b*TOPK + slot];
    for (int j = 0; j < slot; ++j) if (bhi[b*TOPK + j] == h) return;  // dup: block exits
    int S = seqoff[0] + 1;

    __shared__ __align__(16) float4 q4_s[32];
    __shared__ float wts[CHUNK];
    __shared__ float red[8];
    __shared__ __align__(16) float4 vred[8][32];

    int tid = threadIdx.x;
    if (tid < 32) q4_s[tid] = ((const float4*)(ws + WS_QKV + pair*384))[tid];
    __syncthreads();

    // ---- K-pass: pos = tid>>2 in 0..63, dq = tid&3 covers a quarter of the dot ----
    int pos = tid >> 2, dq = tid & 3;
    int s = chunk*CHUNK + pos;
    bool valid = s < S;
    float sc = 0.f;
    if (valid) {
        const float4* kp = (s == S - 1)
            ? (const float4*)(ws + WS_QKV + pair*384 + 128)
            : (const float4*)(kv + ((((size_t)b*SMAX + s)*2 + 0)*H_ + h) * (size_t)D_);
        kp += dq*8;
        #pragma unroll
        for (int i = 0; i < 8; ++i) {
            float4 kvv = kp[i]; float4 qv = q4_s[dq*8 + i];
            sc += kvv.x*qv.x + kvv.y*qv.y + kvv.z*qv.z + kvv.w*qv.w;
        }
    }
    sc += __shfl_xor(sc, 1);
    sc += __shfl_xor(sc, 2);                       // all 4 lanes hold full dot
    float score = valid ? sc * 0.08838834764831845f : -1e30f;

    // block max
    float m = score;
    for (int o = 32; o > 0; o >>= 1) m = fmaxf(m, __shfl_down(m, o));
    int wid = tid >> 6, lane = tid & 63;
    if (lane == 0) red[wid] = m;
    __syncthreads();
    if (tid == 0) red[4] = fmaxf(fmaxf(red[0], red[1]), fmaxf(red[2], red[3]));
    __syncthreads();
    m = red[4];
    float w = (valid && dq == 0) ? expf(score - m) : 0.f;
    if (dq == 0) wts[pos] = w;
    // block sum (only dq==0 contributes)
    float l = w;
    for (int o = 32; o > 0; o >>= 1) l += __shfl_down(l, o);
    if (lane == 0) red[wid] = l;
    __syncthreads();
    if (tid == 0) red[5] = red[0] + red[1] + red[2] + red[3];
    __syncthreads();

    // ---- V-pass: d4 = tid&31 (float4 column), grp = tid>>5 (8 groups x 8 positions) ----
    int d4 = tid & 31, grp = tid >> 5;
    float4 acc = make_float4(0.f, 0.f, 0.f, 0.f);
    #pragma unroll
    for (int i = 0; i < 8; ++i) {
        int t = grp*8 + i;
        int s2 = chunk*CHUNK + t;
        if (s2 < S) {
            const float4* vp = (s2 == S - 1)
                ? (const float4*)(ws + WS_QKV + pair*384 + 256)
                : (const float4*)(kv + ((((size_t)b*SMAX + s2)*2 + 1)*H_ + h) * (size_t)D_);
            float4 vv = vp[d4];
            float wt = wts[t];
            acc.x += wt*vv.x; acc.y += wt*vv.y; acc.z += wt*vv.z; acc.w += wt*vv.w;
        }
    }
    vred[grp][d4] = acc;
    __syncthreads();

    int pc = pair*NCHUNK + chunk;
    if (tid < 32) {
        float4 r = vred[0][tid];
        #pragma unroll
        for (int g = 1; g < 8; ++g) {
            float4 o = vred[g][tid];
            r.x += o.x; r.y += o.y; r.z += o.z; r.w += o.w;
        }
        ((float4*)(ws + WS_PCTX + (size_t)pc*D_))[tid] = r;
    }
    if (tid == 0) { ws[WS_M + pc] = red[4]; ws[WS_L + pc] = red[5]; }
}

// ---------------- kernel 3: combine partials + init out = b_out ----------------
__global__ __launch_bounds__(128) void k_comb(const int* __restrict__ bhi,
    const float* __restrict__ b_out, float* __restrict__ ws, float* __restrict__ out)
{
    int pair = blockIdx.x;
    int b = pair >> 3, slot = pair & 7;
    int tid = threadIdx.x;

    // init out = b_out (all 64 blocks cover 8 batches x 4096 f), BEFORE any early return
    {
        int bb = pair >> 3, fb = pair & 7;
        #pragma unroll
        for (int i = 0; i < 4; ++i) {
            int f = fb*512 + i*128 + tid;
            out[(size_t)bb*E_ + f] = b_out[f];
        }
    }

    int h = bhi[b*TOPK + slot];
    bool dup = false;
    for (int j = 0; j < slot; ++j) if (bhi[b*TOPK + j] == h) dup = true;
    if (dup) { ws[WS_CTX + pair*D_ + tid] = 0.f; return; }

    __shared__ float m_s[NCHUNK], l_s[NCHUNK];
    if (tid < NCHUNK) {
        m_s[tid] = ws[WS_M + pair*NCHUNK + tid];
        l_s[tid] = ws[WS_L + pair*NCHUNK + tid];
    }
    __syncthreads();
    float M = -1e30f;
    for (int i = 0; i < NCHUNK; ++i) M = fmaxf(M, m_s[i]);
    float L = 0.f;
    for (int i = 0; i < NCHUNK; ++i) L += l_s[i] * expf(m_s[i] - M);
    float acc = 0.f;
    for (int i = 0; i < NCHUNK; ++i)
        acc += ws[WS_PCTX + (size_t)(pair*NCHUNK + i)*D_ + tid] * expf(m_s[i] - M);
    ws[WS_CTX + pair*D_ + tid] = acc / L;
}

// ---------------- kernel 4: output projection, union-of-heads ----------------
// block = (head, 128-f block); w_out segment in registers, read ONCE;
// loop over batches that selected this head; atomicAdd into out (init'd by k_comb).
__global__ __launch_bounds__(256) void k_out(const float* __restrict__ w_out,
    const int* __restrict__ bhi, const float* __restrict__ ws, float* __restrict__ out)
{
    int h = blockIdx.x >> 5, fblk = blockIdx.x & 31;

    __shared__ int hs_s[B_*TOPK];
    __shared__ int nsel_s;
    __shared__ int sel_s[B_];     // packed (b<<8)|slot (first matching slot = non-dup)
    __shared__ __align__(16) float ctx_s[B_][D_];
    int tid = threadIdx.x;
    if (tid < B_*TOPK) hs_s[tid] = bhi[tid];
    if (tid == 0) nsel_s = 0;
    __syncthreads();
    if (tid < B_) {
        int b = tid;
        for (int j = 0; j < TOPK; ++j) {
            if (hs_s[b*TOPK + j] == h) {
                int idx = atomicAdd(&nsel_s, 1);
                sel_s[idx] = (b << 8) | j;
                break;
            }
        }
    }
    __syncthreads();
    int nsel = nsel_s;
    if (nsel == 0) return;

    // stage ctx for selecting batches (nsel * 512B)
    for (int t = tid; t < nsel*32; t += 256) {
        int is = t >> 5, q = t & 31;
        int b = sel_s[is] >> 8, slot = sel_s[is] & 255;
        ((float4*)ctx_s[is])[q] =
            ((const float4*)(ws + WS_CTX + (size_t)(b*TOPK + slot)*D_))[q];
    }
    __syncthreads();

    int f_local = tid >> 1, half = tid & 1;   // 128 f x 2 halves
    int f = fblk*128 + f_local;
    const float4* wp = (const float4*)(w_out + (size_t)f*E_ + h*D_) + half*16;
    float4 wv[16];
    #pragma unroll
    for (int i = 0; i < 16; ++i) wv[i] = wp[i];

    for (int is = 0; is < nsel; ++is) {
        const float4* cp = (const float4*)ctx_s[is] + half*16;
        float acc = 0.f;
        #pragma unroll
        for (int i = 0; i < 16; ++i) {
            float4 c = cp[i];
            acc += wv[i].x*c.x + wv[i].y*c.y + wv[i].z*c.z + wv[i].w*c.w;
        }
        acc += __shfl_xor(acc, 1);            // combine the two halves
        if (half == 0) {
            int b = sel_s[is] >> 8;
            atomicAdd(&out[(size_t)b*E_ + f], acc);
        }
    }
}

extern "C" void kernel_launch(void* const* d_in, const int* in_sizes, int n_in,
                              void* d_out, int out_size, void* d_ws, size_t ws_size,
                              hipStream_t stream) {
    const float* x      = (const float*)d_in[0];
    const float* kv     = (const float*)d_in[1];
    const float* w_qkv  = (const float*)d_in[2];
    const float* b_qkv  = (const float*)d_in[3];
    const float* w_out  = (const float*)d_in[4];
    const float* b_out  = (const float*)d_in[5];
    const int*   bhi    = (const int*)d_in[6];
    const int*   seqoff = (const int*)d_in[7];
    float* ws  = (float*)d_ws;
    float* out = (float*)d_out;

    hipLaunchKernelGGL(k_qkv,  dim3(32*384),       dim3(256), 0, stream, x, w_qkv, b_qkv, bhi, ws);
    hipLaunchKernelGGL(k_attn, dim3(NPAIR*NCHUNK), dim3(256), 0, stream, kv, bhi, seqoff, ws);
    hipLaunchKernelGGL(k_comb, dim3(NPAIR),        dim3(128), 0, stream, bhi, b_out, ws, out);
    hipLaunchKernelGGL(k_out,  dim3(H_*32),        dim3(256), 0, stream, w_out, bhi, ws, out);
}